// Round 18
// baseline (3540.062 us; speedup 1.0000x reference)
//
#include <hip/hip_runtime.h>
#include <hip/hip_fp16.h>

#define TPB 256
#define NB_PART 512
#define NB_LOOP 8192

union H8 { float4 f4; __half2 h2[4]; };
union U2H4 { uint2 u2; __half2 h2[2]; };

typedef _Float16 half2v __attribute__((ext_vector_type(2)));

__device__ inline float fdot2(half2v a, half2v b, float c) {
    return __builtin_amdgcn_fdot2(a, b, c, false);
}

__device__ inline void acc_h8(const float4& raw, float* a) {
    H8 u; u.f4 = raw;
#pragma unroll
    for (int i = 0; i < 4; i++) {
        float2 f = __half22float2(u.h2[i]);
        a[2 * i] += f.x;
        a[2 * i + 1] += f.y;
    }
}

// exact pair accumulate (fp32 adds)
__device__ inline void acc_h8x2(const float4& rA, const float4& rB, float* a) {
    H8 uA, uB; uA.f4 = rA; uB.f4 = rB;
#pragma unroll
    for (int i = 0; i < 4; i++) {
        float2 fA = __half22float2(uA.h2[i]);
        float2 fB = __half22float2(uB.h2[i]);
        a[2 * i] += fA.x + fB.x;
        a[2 * i + 1] += fA.y + fB.y;
    }
}

// fast pair accumulate (half pre-add, one rounding per pair)
__device__ inline void acc_h8p(const float4& rA, const float4& rB, float* a) {
    H8 uA, uB; uA.f4 = rA; uB.f4 = rB;
#pragma unroll
    for (int i = 0; i < 4; i++) {
        __half2 s = __hadd2(uA.h2[i], uB.h2[i]);
        float2 f = __half22float2(s);
        a[2 * i] += f.x;
        a[2 * i + 1] += f.y;
    }
}

// ---------------- bucket histogram ----------------
__global__ __launch_bounds__(TPB) void k_bhist(const int* __restrict__ dst,
                                               int* __restrict__ bhist, int E, int shift) {
    __shared__ int h[256];
    int tid = threadIdx.x;
    for (int i = tid; i < 256; i += TPB) h[i] = 0;
    __syncthreads();
    int stride = gridDim.x * TPB;
    for (int e = blockIdx.x * TPB + tid; e < E; e += stride)
        atomicAdd(&h[dst[e] >> shift], 1);
    __syncthreads();
    for (int i = tid; i < 256; i += TPB)
        if (h[i]) atomicAdd(&bhist[i], h[i]);
}

// ---------------- scan 256 buckets ----------------
__global__ void k_bscan(const int* __restrict__ bhist, int* __restrict__ bstart,
                        int* __restrict__ gcursor, int nbuck) {
    __shared__ int s[256];
    int tid = threadIdx.x;
    int v = bhist[tid];
    s[tid] = v;
    __syncthreads();
    for (int off = 1; off < 256; off <<= 1) {
        int t = (tid >= off) ? s[tid - off] : 0;
        __syncthreads();
        s[tid] += t;
        __syncthreads();
    }
    int excl = s[tid] - v;
    bstart[tid] = excl;
    if (tid == 255) bstart[256] = s[255];
    if (tid < nbuck) gcursor[tid] = excl;
}

// ---------------- pass 1: partition edges into dst-buckets ----------------
// record = (dst_low << 18) | src   (requires N <= 2^18)
__global__ __launch_bounds__(TPB) void k_part(const int* __restrict__ src,
                                              const int* __restrict__ dst,
                                              int* __restrict__ gcursor,
                                              unsigned* __restrict__ staging,
                                              int E, int shift) {
    __shared__ int hist[256];
    __shared__ int base[256];
    int tid = threadIdx.x;
    long long per = (E + gridDim.x - 1) / gridDim.x;
    int e0 = (int)((long long)blockIdx.x * per);
    int e1 = (int)min((long long)E, (long long)e0 + per);
    for (int i = tid; i < 256; i += TPB) hist[i] = 0;
    __syncthreads();
    for (int e = e0 + tid; e < e1; e += TPB) {
        int b = dst[e] >> shift;
        atomicAdd(&hist[b], 1);
    }
    __syncthreads();
    for (int i = tid; i < 256; i += TPB) {
        int c = hist[i];
        base[i] = (c > 0) ? atomicAdd(&gcursor[i], c) : 0;
        hist[i] = 0;
    }
    __syncthreads();
    unsigned lmask = (1u << shift) - 1u;
    for (int e = e0 + tid; e < e1; e += TPB) {
        int d = dst[e];
        int b = d >> shift;
        int p = base[b] + atomicAdd(&hist[b], 1);
        staging[p] = (((unsigned)d & lmask) << 18) | (unsigned)src[e];
    }
}

// ---- per-bucket degree + dinv + row_start (in-bucket prefix scan) ----
__global__ __launch_bounds__(TPB) void k_deg_scan(const unsigned* __restrict__ staging,
                                                  const int* __restrict__ bstart,
                                                  int* __restrict__ deg,
                                                  float* __restrict__ dinv,
                                                  int* __restrict__ row_start,
                                                  int N, int shift) {
    __shared__ int cnt[4096];
    __shared__ int sums[TPB];
    int b = blockIdx.x, tid = threadIdx.x;
    int base = b << shift;
    int nn = min(1 << shift, N - base);
    for (int i = tid; i < nn; i += TPB) cnt[i] = 0;
    __syncthreads();
    int rs = bstart[b], re = bstart[b + 1];
    for (int j = rs + tid; j < re; j += TPB) atomicAdd(&cnt[staging[j] >> 18], 1);
    __syncthreads();
    int per = (nn + TPB - 1) / TPB;
    int myb = tid * per;
    int loc = 0;
    for (int c = 0; c < per; c++) {
        int idx = myb + c;
        if (idx < nn) loc += cnt[idx];
    }
    sums[tid] = loc;
    __syncthreads();
    for (int off = 1; off < TPB; off <<= 1) {
        int t = (tid >= off) ? sums[tid - off] : 0;
        __syncthreads();
        sums[tid] += t;
        __syncthreads();
    }
    int running = rs + sums[tid] - loc;
    for (int c = 0; c < per; c++) {
        int idx = myb + c;
        if (idx < nn) {
            int v = cnt[idx];
            deg[base + idx] = v;
            dinv[base + idx] = rsqrtf((float)v + 1.0f);
            row_start[base + idx] = running;
            running += v;
        }
    }
}

// ---------------- pass 2: per-bucket scatter with LDS cursors ----------------
__global__ __launch_bounds__(TPB) void k_scatter2(const unsigned* __restrict__ staging,
                                                  const int* __restrict__ row_start,
                                                  int* __restrict__ csr,
                                                  int N, int E, int shift) {
    __shared__ int curs[4096];
    int b = blockIdx.x;
    int tid = threadIdx.x;
    int base = b << shift;
    int nn = min(1 << shift, N - base);
    for (int i = tid; i < nn; i += TPB) curs[i] = row_start[base + i];
    __syncthreads();
    int rs = row_start[base];
    int re = (base + nn < N) ? row_start[base + nn] : E;
    for (int j = rs + tid; j < re; j += TPB) {
        unsigned rec = staging[j];
        int s = rec & 0x3FFFF;
        int dl = rec >> 18;
        int p = atomicAdd(&curs[dl], 1);
        csr[p] = s;
    }
}

// ---------------- prescale to fp16: xp = half(dinv[n] * x) ----------------
__global__ __launch_bounds__(TPB) void k_xp16(const float* __restrict__ x,
                                              const float* __restrict__ dinv,
                                              __half* __restrict__ xp, int N) {
    int t = blockIdx.x * TPB + threadIdx.x;
    if (t < N * 8) xp[t] = __float2half(dinv[t >> 3] * x[t]);
}

// ---- fused layer 0: pull8 + self + 8->64 matmul + tanh -> h0p16 (16 lanes/node) ----
__global__ __launch_bounds__(TPB) void k_l0fused(const int* __restrict__ row_start,
                                                 const int* __restrict__ deg,
                                                 const int* __restrict__ csr,
                                                 const float* __restrict__ dinv,
                                                 const __half* __restrict__ xp,
                                                 const float* __restrict__ W0,
                                                 const float* __restrict__ b0,
                                                 __half* __restrict__ h0p, int N) {
    int t = blockIdx.x * TPB + threadIdx.x;
    int node = t >> 4;
    int ll = t & 15;
    if (node >= N) return;
    int s0 = row_start[node], dn = deg[node];
    const float4* x4 = (const float4*)xp;
    float a[8] = {0, 0, 0, 0, 0, 0, 0, 0};
    for (int j = ll; j < dn; j += 16) acc_h8(x4[csr[s0 + j]], a);
#pragma unroll
    for (int off = 1; off < 16; off <<= 1) {
#pragma unroll
        for (int i = 0; i < 8; i++) a[i] += __shfl_xor(a[i], off, 64);
    }
    float di = dinv[node];
    H8 u; u.f4 = x4[node];
    float row[8];
#pragma unroll
    for (int i = 0; i < 4; i++) {
        float2 f = __half22float2(u.h2[i]);
        row[2 * i] = di * (a[2 * i] + f.x);
        row[2 * i + 1] = di * (a[2 * i + 1] + f.y);
    }
    float o[4];
#pragma unroll
    for (int c = 0; c < 4; c++) {
        int f = ll * 4 + c;
        float acc = b0[f];
#pragma unroll
        for (int k = 0; k < 8; k++) acc += row[k] * W0[k * 64 + f];
        o[c] = di * tanhf(acc);
    }
    U2H4 w;
    w.h2[0] = __floats2half2_rn(o[0], o[1]);
    w.h2[1] = __floats2half2_rn(o[2], o[3]);
    ((uint2*)h0p)[(size_t)node * 16 + ll] = w.u2;
}

// ---- fused pull64(h0p16) + self + W1 + relu + W2 + dinv-scale -> t2p16 ----
// Lean 1-node-per-wave gather; fdot2 matmuls; W1 column preloaded into
// registers (32 half2v, lane-owned); W2 in LDS. ~8 waves/SIMD.
__global__ __launch_bounds__(TPB) void k_pullmmf(const int* __restrict__ row_start,
                                                 const int* __restrict__ deg,
                                                 const int* __restrict__ csr,
                                                 const float* __restrict__ dinv,
                                                 const __half* __restrict__ h0p,
                                                 const float* __restrict__ W1,
                                                 const float* __restrict__ b1,
                                                 const float* __restrict__ W2,
                                                 __half* __restrict__ t2p, int N) {
    __shared__ half2v W1p[32 * 64];  // staging only; copied to regs below
    __shared__ half2v W2p[32 * 32];  // W2p[k2*32+f] = (W2[2k2][f], W2[2k2+1][f])
    __shared__ half2v rowsp[4][32];  // 64 halves per wave-group
    __shared__ half2v h1p[4][32];    // 64 halves per wave-group
    int tid = threadIdx.x;
    for (int i = tid; i < 32 * 64; i += TPB) {
        int k2 = i >> 6, c = i & 63;
        half2v v = {(_Float16)W1[(2 * k2) * 64 + c], (_Float16)W1[(2 * k2 + 1) * 64 + c]};
        W1p[i] = v;
    }
    for (int i = tid; i < 32 * 32; i += TPB) {
        int k2 = i >> 5, f = i & 31;
        half2v v = {(_Float16)W2[(2 * k2) * 32 + f], (_Float16)W2[(2 * k2 + 1) * 32 + f]};
        W2p[i] = v;
    }
    __syncthreads();
    int grp = tid >> 6, lane = tid & 63;
    int q = lane & 7, eg = lane >> 3;   // 8 quads x 8 halves; 8 edge groups
    int hf = lane >> 5, f = lane & 31;  // W2 split
    // preload this lane's W1 column into registers (32 VGPRs)
    half2v regW1[32];
#pragma unroll
    for (int k2 = 0; k2 < 32; k2++) regW1[k2] = W1p[k2 * 64 + lane];
    const float4* h4 = (const float4*)h0p;
    int n4 = (N + 3) >> 2;
    for (int blk = blockIdx.x; blk < n4; blk += gridDim.x) {
        int node = blk * 4 + grp;
        if (node >= N) continue;
        int s0 = row_start[node], dn = deg[node];
        float a[8] = {0, 0, 0, 0, 0, 0, 0, 0};
        int j = eg;
        for (; j + 8 < dn; j += 16) {
            int sA = csr[s0 + j];
            int sB = csr[s0 + j + 8];
            float4 vA = h4[(size_t)sA * 8 + q];
            float4 vB = h4[(size_t)sB * 8 + q];
            acc_h8p(vA, vB, a);
        }
        if (j < dn) acc_h8(h4[(size_t)csr[s0 + j] * 8 + q], a);
#pragma unroll
        for (int off = 8; off < 64; off <<= 1) {
#pragma unroll
            for (int i = 0; i < 8; i++) a[i] += __shfl_xor(a[i], off, 64);
        }
        float di = dinv[node];
        if (eg == 0) {
            H8 u; u.f4 = h4[(size_t)node * 8 + q];
#pragma unroll
            for (int i = 0; i < 4; i++) {
                float2 fv = __half22float2(u.h2[i]);
                float r0 = di * (a[2 * i] + fv.x);
                float r1 = di * (a[2 * i + 1] + fv.y);
                half2v rp = {(_Float16)r0, (_Float16)r1};
                rowsp[grp][q * 4 + i] = rp;
            }
        }
        // wave-private LDS (compiler-ordered within the wave, no barrier);
        // rowsp reads are lane-uniform broadcasts.
        float acc = b1[lane];
#pragma unroll 8
        for (int k2 = 0; k2 < 32; k2++)
            acc = fdot2(rowsp[grp][k2], regW1[k2], acc);
        float h1v = fmaxf(acc, 0.0f);
        ((_Float16*)h1p[grp])[lane] = (_Float16)h1v;
        float p = 0.0f;
#pragma unroll 8
        for (int j2 = 0; j2 < 16; j2++) {
            int k2 = hf * 16 + j2;
            p = fdot2(h1p[grp][k2], W2p[k2 * 32 + f], p);
        }
        p += __shfl_xor(p, 32, 64);
        if (hf == 0) t2p[(size_t)node * 32 + f] = __float2half(di * p);
    }
}

// ---- fused: pull32(t2p16)+self -> h2=relu -> t3p16 = half(di*(h2@W3)) ----
// fdot2 matmul; W3 column in registers (16 half2v); rows as half2 in LDS.
__global__ __launch_bounds__(TPB) void k_pullfinmm32h(const int* __restrict__ row_start,
                                                      const int* __restrict__ deg,
                                                      const int* __restrict__ csr,
                                                      const float* __restrict__ dinv,
                                                      const __half* __restrict__ t2p,
                                                      const float* __restrict__ b2,
                                                      const float* __restrict__ W3,
                                                      __half* __restrict__ t3p, int N) {
    __shared__ half2v W3p[16 * 32];      // W3p[k2*32+f] = (W3[2k2][f], W3[2k2+1][f])
    __shared__ half2v rowsp[4][2][16];   // 32 halves per node slot
    int tid = threadIdx.x;
    for (int i = tid; i < 16 * 32; i += TPB) {
        int k2 = i >> 5, f = i & 31;
        half2v v = {(_Float16)W3[(2 * k2) * 32 + f], (_Float16)W3[(2 * k2 + 1) * 32 + f]};
        W3p[i] = v;
    }
    __syncthreads();
    int grp = tid >> 6, lane = tid & 63;
    int hw = lane >> 5, ll = lane & 31;
    int q = ll & 3, eg = ll >> 2;
    // preload W3 column for output feature ll (16 VGPRs)
    half2v regW3[16];
#pragma unroll
    for (int k2 = 0; k2 < 16; k2++) regW3[k2] = W3p[k2 * 32 + ll];
    const float4* h4 = (const float4*)t2p;
    int n8 = (N + 7) >> 3;
    for (int blk = blockIdx.x; blk < n8; blk += gridDim.x) {
        int node = blk * 8 + grp * 2 + hw;
        if (node < N) {
            float di = dinv[node];
            int s0 = row_start[node], dn = deg[node];
            float a[8] = {0, 0, 0, 0, 0, 0, 0, 0};
            int j = eg;
            for (; j + 8 < dn; j += 16) {
                int sA = csr[s0 + j];
                int sB = csr[s0 + j + 8];
                float4 vA = h4[(size_t)sA * 4 + q];
                float4 vB = h4[(size_t)sB * 4 + q];
                acc_h8x2(vA, vB, a);
            }
            if (j < dn) acc_h8(h4[(size_t)csr[s0 + j] * 4 + q], a);
#pragma unroll
            for (int off = 4; off < 32; off <<= 1) {
#pragma unroll
                for (int i = 0; i < 8; i++) a[i] += __shfl_xor(a[i], off, 64);
            }
            if (eg == 0) {
                H8 u; u.f4 = h4[(size_t)node * 4 + q];
#pragma unroll
                for (int i = 0; i < 4; i++) {
                    float2 fv = __half22float2(u.h2[i]);
                    float r0 = fmaxf(di * (a[2 * i] + fv.x) + b2[q * 8 + 2 * i], 0.0f);
                    float r1 = fmaxf(di * (a[2 * i + 1] + fv.y) + b2[q * 8 + 2 * i + 1], 0.0f);
                    half2v rp = {(_Float16)r0, (_Float16)r1};
                    rowsp[grp][hw][q * 4 + i] = rp;
                }
            }
            float a2 = 0.0f;
#pragma unroll 8
            for (int k2 = 0; k2 < 16; k2++)
                a2 = fdot2(rowsp[grp][hw][k2], regW3[k2], a2);
            t3p[(size_t)node * 32 + ll] = __float2half(di * a2);
        }
    }
}

// ---- fused: pull32(t3p16)+self -> h3 = relu (fp32). 2 nodes/wave ----
__global__ __launch_bounds__(TPB) void k_pullfin3h(const int* __restrict__ row_start,
                                                   const int* __restrict__ deg,
                                                   const int* __restrict__ csr,
                                                   const float* __restrict__ dinv,
                                                   const __half* __restrict__ t3p,
                                                   const float* __restrict__ b3,
                                                   float* __restrict__ h3, int N) {
    int t = blockIdx.x * TPB + threadIdx.x;
    int node = t >> 5;
    int ll = t & 31;
    if (node >= N) return;
    int q = ll & 3, eg = ll >> 2;
    int s0 = row_start[node], dn = deg[node];
    const float4* h4 = (const float4*)t3p;
    float a[8] = {0, 0, 0, 0, 0, 0, 0, 0};
    int j = eg;
    for (; j + 8 < dn; j += 16) {
        int sA = csr[s0 + j];
        int sB = csr[s0 + j + 8];
        float4 vA = h4[(size_t)sA * 4 + q];
        float4 vB = h4[(size_t)sB * 4 + q];
        acc_h8x2(vA, vB, a);
    }
    if (j < dn) acc_h8(h4[(size_t)csr[s0 + j] * 4 + q], a);
#pragma unroll
    for (int off = 4; off < 32; off <<= 1) {
#pragma unroll
        for (int i = 0; i < 8; i++) a[i] += __shfl_xor(a[i], off, 64);
    }
    if (eg == 0) {
        float di = dinv[node];
        H8 u; u.f4 = h4[(size_t)node * 4 + q];
        float r[8];
#pragma unroll
        for (int i = 0; i < 4; i++) {
            float2 f = __half22float2(u.h2[i]);
            r[2 * i] = fmaxf(di * (a[2 * i] + f.x) + b3[q * 8 + 2 * i], 0.0f);
            r[2 * i + 1] = fmaxf(di * (a[2 * i + 1] + f.y) + b3[q * 8 + 2 * i + 1], 0.0f);
        }
        float4* o = (float4*)h3 + (size_t)node * 8 + q * 2;
        o[0] = make_float4(r[0], r[1], r[2], r[3]);
        o[1] = make_float4(r[4], r[5], r[6], r[7]);
    }
}

// ---------------- graph boundaries (batch_index is sorted) ----------------
__global__ __launch_bounds__(TPB) void k_gbound(const int* __restrict__ batch,
                                                int* __restrict__ start, int N, int G) {
    int g = blockIdx.x * TPB + threadIdx.x;
    if (g > G) return;
    int lo = 0, hi = N;
    while (lo < hi) {
        int mid = (lo + hi) >> 1;
        if (batch[mid] < g) lo = mid + 1;
        else hi = mid;
    }
    start[g] = lo;
}

// ---------------- pooling: one block per graph, no atomics ----------------
__global__ __launch_bounds__(TPB) void k_pool2(const float* __restrict__ h,
                                               const int* __restrict__ start,
                                               float* __restrict__ gmax,
                                               float* __restrict__ gsum, int G) {
    __shared__ float smax[8][32];
    __shared__ float ssum[8][32];
    int g = blockIdx.x;
    int s = start[g], e = start[g + 1];
    int tid = threadIdx.x;
    int nl = tid >> 5, f = tid & 31;
    float mx = 0.0f, sm = 0.0f;
    for (int n = s + nl; n < e; n += 8) {
        float v = h[(size_t)n * 32 + f];
        mx = fmaxf(mx, v);
        sm += v;
    }
    smax[nl][f] = mx;
    ssum[nl][f] = sm;
    __syncthreads();
    if (nl == 0) {
#pragma unroll
        for (int k = 1; k < 8; k++) {
            mx = fmaxf(mx, smax[k][f]);
            sm += ssum[k][f];
        }
        gmax[g * 32 + f] = mx;
        gsum[g * 32 + f] = sm;
    }
}

// ---------------- head ----------------
__global__ __launch_bounds__(TPB) void k_out(const float* __restrict__ gmax,
                                             const float* __restrict__ gsum,
                                             const int* __restrict__ start,
                                             const float* __restrict__ Wout,
                                             const float* __restrict__ bout,
                                             float* __restrict__ out, int G) {
    int t = blockIdx.x * TPB + threadIdx.x;
    if (t >= G * 10) return;
    int g = t / 10, j = t % 10;
    float c = (float)(start[g + 1] - start[g]);
    float inv = 1.0f / fmaxf(c, 1.0f);
    float a = bout[j];
#pragma unroll
    for (int k = 0; k < 32; k++) a += gmax[g * 32 + k] * Wout[k * 10 + j];
#pragma unroll
    for (int k = 0; k < 32; k++) a += (gsum[g * 32 + k] * inv) * Wout[(32 + k) * 10 + j];
    out[t] = a;
}

static inline int cdiv(long long a, int b) { return (int)((a + b - 1) / b); }

extern "C" void kernel_launch(void* const* d_in, const int* in_sizes, int n_in,
                              void* d_out, int out_size, void* d_ws, size_t ws_size,
                              hipStream_t stream) {
    const float* x    = (const float*)d_in[0];
    const int*   ei   = (const int*)d_in[1];
    const int*   bidx = (const int*)d_in[2];
    const float* W0 = (const float*)d_in[3];
    const float* b0 = (const float*)d_in[4];
    const float* W1 = (const float*)d_in[5];
    const float* b1 = (const float*)d_in[6];
    const float* W2 = (const float*)d_in[7];
    const float* b2 = (const float*)d_in[8];
    const float* W3 = (const float*)d_in[9];
    const float* b3 = (const float*)d_in[10];
    const float* Wout = (const float*)d_in[11];
    const float* bout = (const float*)d_in[12];
    float* out = (float*)d_out;

    const int N = in_sizes[0] / 8;
    const int E = in_sizes[1] / 2;
    const int G = out_size / 10;
    const int* src = ei;
    const int* dst = ei + E;

    int shift = 10;
    while (((N + (1 << shift) - 1) >> shift) > 256) shift++;
    const int nbuck = (N + (1 << shift) - 1) >> shift;

    // ---- workspace layout (16B-aligned chunks) ----
    char* w = (char*)d_ws;
    int*   deg_i     = (int*)w;    w += (size_t)N * 4;
    int*   row_start = (int*)w;    w += (size_t)N * 4;
    float* dinv      = (float*)w;  w += (size_t)N * 4;
    float* gmax      = (float*)w;  w += (size_t)G * 32 * 4;
    float* gsum      = (float*)w;  w += (size_t)G * 32 * 4;
    int*   gstart    = (int*)w;    w += (size_t)(G + 4) * 4;
    int*   bhist     = (int*)w;    w += 256 * 4;
    int*   bstart    = (int*)w;    w += 260 * 4;
    int*   csr       = (int*)w;    w += (size_t)E * 4;
    float* bufA      = (float*)w;  w += (size_t)N * 64 * 4;
    float* bufB      = (float*)w;  w += (size_t)N * 64 * 4;
    // transient aliases (stream-ordered lifetimes):
    unsigned* staging = (unsigned*)bufA;   // E recs; dead after k_scatter2
    int*      gcursor = (int*)bufB;        // nbuck; dead after k_part
    __half* xp16  = (__half*)bufB;         // N*8 h; written after k_part; dead after l0fused
    __half* h0p16 = (__half*)bufA;         // N*64 h; dead after k_pullmmf
    __half* t2p16 = (__half*)bufB;         // N*32 h; dead after k_pullfinmm32h
    __half* t3p16 = (__half*)bufA;         // N*32 h; dead after k_pullfin3h
    float*  h3    = (float*)bufB;          // N*32 f

    // ---- CSR build ----
    hipMemsetAsync(bhist, 0, 256 * 4, stream);
    k_bhist<<<256, TPB, 0, stream>>>(dst, bhist, E, shift);
    k_bscan<<<1, 256, 0, stream>>>(bhist, bstart, gcursor, nbuck);
    k_part<<<NB_PART, TPB, 0, stream>>>(src, dst, gcursor, staging, E, shift);
    k_deg_scan<<<nbuck, TPB, 0, stream>>>(staging, bstart, deg_i, dinv, row_start, N, shift);
    k_scatter2<<<nbuck, TPB, 0, stream>>>(staging, row_start, csr, N, E, shift);
    k_gbound<<<cdiv(G + 1, TPB), TPB, 0, stream>>>(bidx, gstart, N, G);

    // ---- layer 0 (fp16 gathers, fp32 math) ----
    k_xp16<<<cdiv((long long)N * 8, TPB), TPB, 0, stream>>>(x, dinv, xp16, N);
    k_l0fused<<<cdiv(N, 16), TPB, 0, stream>>>(row_start, deg_i, csr, dinv, xp16, W0, b0,
                                               h0p16, N);

    // ---- layers 1+2a fused: pull64 + W1 + relu + W2 + scale -> t2p16 ----
    k_pullmmf<<<NB_LOOP, TPB, 0, stream>>>(row_start, deg_i, csr, dinv, h0p16, W1, b1, W2,
                                           t2p16, N);

    // ---- layer 2b+3a: fused pull32 + fin + W3 + scale -> t3p16 ----
    k_pullfinmm32h<<<NB_LOOP, TPB, 0, stream>>>(row_start, deg_i, csr, dinv, t2p16, b2,
                                                W3, t3p16, N);

    // ---- layer 3b: fused pull32 + finalize -> h3 (flat grid) ----
    k_pullfin3h<<<cdiv(N, 8), TPB, 0, stream>>>(row_start, deg_i, csr, dinv, t3p16, b3, h3, N);

    // ---- pooling + head ----
    k_pool2<<<G, TPB, 0, stream>>>(h3, gstart, gmax, gsum, G);
    k_out<<<cdiv((long long)G * 10, TPB), TPB, 0, stream>>>(gmax, gsum, gstart, Wout, bout,
                                                            out, G);
}

// Round 19
// 614.753 us; speedup vs baseline: 5.7585x; 5.7585x over previous
//
#include <hip/hip_runtime.h>
#include <hip/hip_fp16.h>

#define TPB 256
#define NB_PART 512
#define NB_LOOP 8192

union H8 { float4 f4; __half2 h2[4]; };
union U2H4 { uint2 u2; __half2 h2[2]; };

typedef _Float16 half2v __attribute__((ext_vector_type(2)));

__device__ inline float fdot2(half2v a, half2v b, float c) {
    return __builtin_amdgcn_fdot2(a, b, c, false);
}

__device__ inline void acc_h8(const float4& raw, float* a) {
    H8 u; u.f4 = raw;
#pragma unroll
    for (int i = 0; i < 4; i++) {
        float2 f = __half22float2(u.h2[i]);
        a[2 * i] += f.x;
        a[2 * i + 1] += f.y;
    }
}

// exact pair accumulate (fp32 adds)
__device__ inline void acc_h8x2(const float4& rA, const float4& rB, float* a) {
    H8 uA, uB; uA.f4 = rA; uB.f4 = rB;
#pragma unroll
    for (int i = 0; i < 4; i++) {
        float2 fA = __half22float2(uA.h2[i]);
        float2 fB = __half22float2(uB.h2[i]);
        a[2 * i] += fA.x + fB.x;
        a[2 * i + 1] += fA.y + fB.y;
    }
}

// fast pair accumulate (half pre-add, one rounding per pair)
__device__ inline void acc_h8p(const float4& rA, const float4& rB, float* a) {
    H8 uA, uB; uA.f4 = rA; uB.f4 = rB;
#pragma unroll
    for (int i = 0; i < 4; i++) {
        __half2 s = __hadd2(uA.h2[i], uB.h2[i]);
        float2 f = __half22float2(s);
        a[2 * i] += f.x;
        a[2 * i + 1] += f.y;
    }
}

// ---------------- bucket histogram ----------------
__global__ __launch_bounds__(TPB) void k_bhist(const int* __restrict__ dst,
                                               int* __restrict__ bhist, int E, int shift) {
    __shared__ int h[256];
    int tid = threadIdx.x;
    for (int i = tid; i < 256; i += TPB) h[i] = 0;
    __syncthreads();
    int stride = gridDim.x * TPB;
    for (int e = blockIdx.x * TPB + tid; e < E; e += stride)
        atomicAdd(&h[dst[e] >> shift], 1);
    __syncthreads();
    for (int i = tid; i < 256; i += TPB)
        if (h[i]) atomicAdd(&bhist[i], h[i]);
}

// ---------------- scan 256 buckets ----------------
__global__ void k_bscan(const int* __restrict__ bhist, int* __restrict__ bstart,
                        int* __restrict__ gcursor, int nbuck) {
    __shared__ int s[256];
    int tid = threadIdx.x;
    int v = bhist[tid];
    s[tid] = v;
    __syncthreads();
    for (int off = 1; off < 256; off <<= 1) {
        int t = (tid >= off) ? s[tid - off] : 0;
        __syncthreads();
        s[tid] += t;
        __syncthreads();
    }
    int excl = s[tid] - v;
    bstart[tid] = excl;
    if (tid == 255) bstart[256] = s[255];
    if (tid < nbuck) gcursor[tid] = excl;
}

// ---------------- pass 1: partition edges into dst-buckets ----------------
// record = (dst_low << 18) | src   (requires N <= 2^18)
__global__ __launch_bounds__(TPB) void k_part(const int* __restrict__ src,
                                              const int* __restrict__ dst,
                                              int* __restrict__ gcursor,
                                              unsigned* __restrict__ staging,
                                              int E, int shift) {
    __shared__ int hist[256];
    __shared__ int base[256];
    int tid = threadIdx.x;
    long long per = (E + gridDim.x - 1) / gridDim.x;
    int e0 = (int)((long long)blockIdx.x * per);
    int e1 = (int)min((long long)E, (long long)e0 + per);
    for (int i = tid; i < 256; i += TPB) hist[i] = 0;
    __syncthreads();
    for (int e = e0 + tid; e < e1; e += TPB) {
        int b = dst[e] >> shift;
        atomicAdd(&hist[b], 1);
    }
    __syncthreads();
    for (int i = tid; i < 256; i += TPB) {
        int c = hist[i];
        base[i] = (c > 0) ? atomicAdd(&gcursor[i], c) : 0;
        hist[i] = 0;
    }
    __syncthreads();
    unsigned lmask = (1u << shift) - 1u;
    for (int e = e0 + tid; e < e1; e += TPB) {
        int d = dst[e];
        int b = d >> shift;
        int p = base[b] + atomicAdd(&hist[b], 1);
        staging[p] = (((unsigned)d & lmask) << 18) | (unsigned)src[e];
    }
}

// ---- per-bucket degree + dinv + row_start (in-bucket prefix scan) ----
__global__ __launch_bounds__(TPB) void k_deg_scan(const unsigned* __restrict__ staging,
                                                  const int* __restrict__ bstart,
                                                  int* __restrict__ deg,
                                                  float* __restrict__ dinv,
                                                  int* __restrict__ row_start,
                                                  int N, int shift) {
    __shared__ int cnt[4096];
    __shared__ int sums[TPB];
    int b = blockIdx.x, tid = threadIdx.x;
    int base = b << shift;
    int nn = min(1 << shift, N - base);
    for (int i = tid; i < nn; i += TPB) cnt[i] = 0;
    __syncthreads();
    int rs = bstart[b], re = bstart[b + 1];
    for (int j = rs + tid; j < re; j += TPB) atomicAdd(&cnt[staging[j] >> 18], 1);
    __syncthreads();
    int per = (nn + TPB - 1) / TPB;
    int myb = tid * per;
    int loc = 0;
    for (int c = 0; c < per; c++) {
        int idx = myb + c;
        if (idx < nn) loc += cnt[idx];
    }
    sums[tid] = loc;
    __syncthreads();
    for (int off = 1; off < TPB; off <<= 1) {
        int t = (tid >= off) ? sums[tid - off] : 0;
        __syncthreads();
        sums[tid] += t;
        __syncthreads();
    }
    int running = rs + sums[tid] - loc;
    for (int c = 0; c < per; c++) {
        int idx = myb + c;
        if (idx < nn) {
            int v = cnt[idx];
            deg[base + idx] = v;
            dinv[base + idx] = rsqrtf((float)v + 1.0f);
            row_start[base + idx] = running;
            running += v;
        }
    }
}

// ---------------- pass 2: per-bucket scatter with LDS cursors ----------------
__global__ __launch_bounds__(TPB) void k_scatter2(const unsigned* __restrict__ staging,
                                                  const int* __restrict__ row_start,
                                                  int* __restrict__ csr,
                                                  int N, int E, int shift) {
    __shared__ int curs[4096];
    int b = blockIdx.x;
    int tid = threadIdx.x;
    int base = b << shift;
    int nn = min(1 << shift, N - base);
    for (int i = tid; i < nn; i += TPB) curs[i] = row_start[base + i];
    __syncthreads();
    int rs = row_start[base];
    int re = (base + nn < N) ? row_start[base + nn] : E;
    for (int j = rs + tid; j < re; j += TPB) {
        unsigned rec = staging[j];
        int s = rec & 0x3FFFF;
        int dl = rec >> 18;
        int p = atomicAdd(&curs[dl], 1);
        csr[p] = s;
    }
}

// ---------------- prescale to fp16: xp = half(dinv[n] * x) ----------------
__global__ __launch_bounds__(TPB) void k_xp16(const float* __restrict__ x,
                                              const float* __restrict__ dinv,
                                              __half* __restrict__ xp, int N) {
    int t = blockIdx.x * TPB + threadIdx.x;
    if (t < N * 8) xp[t] = __float2half(dinv[t >> 3] * x[t]);
}

// ---- fused layer 0: pull8 + self + 8->64 matmul + tanh -> h0p16 (16 lanes/node) ----
__global__ __launch_bounds__(TPB) void k_l0fused(const int* __restrict__ row_start,
                                                 const int* __restrict__ deg,
                                                 const int* __restrict__ csr,
                                                 const float* __restrict__ dinv,
                                                 const __half* __restrict__ xp,
                                                 const float* __restrict__ W0,
                                                 const float* __restrict__ b0,
                                                 __half* __restrict__ h0p, int N) {
    int t = blockIdx.x * TPB + threadIdx.x;
    int node = t >> 4;
    int ll = t & 15;
    if (node >= N) return;
    int s0 = row_start[node], dn = deg[node];
    const float4* x4 = (const float4*)xp;
    float a[8] = {0, 0, 0, 0, 0, 0, 0, 0};
    for (int j = ll; j < dn; j += 16) acc_h8(x4[csr[s0 + j]], a);
#pragma unroll
    for (int off = 1; off < 16; off <<= 1) {
#pragma unroll
        for (int i = 0; i < 8; i++) a[i] += __shfl_xor(a[i], off, 64);
    }
    float di = dinv[node];
    H8 u; u.f4 = x4[node];
    float row[8];
#pragma unroll
    for (int i = 0; i < 4; i++) {
        float2 f = __half22float2(u.h2[i]);
        row[2 * i] = di * (a[2 * i] + f.x);
        row[2 * i + 1] = di * (a[2 * i + 1] + f.y);
    }
    float o[4];
#pragma unroll
    for (int c = 0; c < 4; c++) {
        int f = ll * 4 + c;
        float acc = b0[f];
#pragma unroll
        for (int k = 0; k < 8; k++) acc += row[k] * W0[k * 64 + f];
        o[c] = di * tanhf(acc);
    }
    U2H4 w;
    w.h2[0] = __floats2half2_rn(o[0], o[1]);
    w.h2[1] = __floats2half2_rn(o[2], o[3]);
    ((uint2*)h0p)[(size_t)node * 16 + ll] = w.u2;
}

// ---- fused pull64(h0p16) + self + W1 + relu + W2 + dinv-scale -> t2p16 ----
// R17-proven: lean 1-node-per-wave gather; fdot2 matmuls with weights in LDS
// (dynamic indexing is LDS-safe; register arrays would spill to scratch).
__global__ __launch_bounds__(TPB) void k_pullmmf(const int* __restrict__ row_start,
                                                 const int* __restrict__ deg,
                                                 const int* __restrict__ csr,
                                                 const float* __restrict__ dinv,
                                                 const __half* __restrict__ h0p,
                                                 const float* __restrict__ W1,
                                                 const float* __restrict__ b1,
                                                 const float* __restrict__ W2,
                                                 __half* __restrict__ t2p, int N) {
    __shared__ half2v W1p[32 * 64];  // W1p[k2*64+c] = (W1[2k2][c], W1[2k2+1][c])
    __shared__ half2v W2p[32 * 32];  // W2p[k2*32+f] = (W2[2k2][f], W2[2k2+1][f])
    __shared__ half2v rowsp[4][32];  // 64 halves per wave-group
    __shared__ half2v h1p[4][32];    // 64 halves per wave-group
    int tid = threadIdx.x;
    for (int i = tid; i < 32 * 64; i += TPB) {
        int k2 = i >> 6, c = i & 63;
        half2v v = {(_Float16)W1[(2 * k2) * 64 + c], (_Float16)W1[(2 * k2 + 1) * 64 + c]};
        W1p[i] = v;
    }
    for (int i = tid; i < 32 * 32; i += TPB) {
        int k2 = i >> 5, f = i & 31;
        half2v v = {(_Float16)W2[(2 * k2) * 32 + f], (_Float16)W2[(2 * k2 + 1) * 32 + f]};
        W2p[i] = v;
    }
    __syncthreads();
    int grp = tid >> 6, lane = tid & 63;
    int q = lane & 7, eg = lane >> 3;   // 8 quads x 8 halves; 8 edge groups
    int hf = lane >> 5, f = lane & 31;  // W2 split
    const float4* h4 = (const float4*)h0p;
    int n4 = (N + 3) >> 2;
    for (int blk = blockIdx.x; blk < n4; blk += gridDim.x) {
        int node = blk * 4 + grp;
        if (node >= N) continue;
        int s0 = row_start[node], dn = deg[node];
        float a[8] = {0, 0, 0, 0, 0, 0, 0, 0};
        int j = eg;
        for (; j + 8 < dn; j += 16) {
            int sA = csr[s0 + j];
            int sB = csr[s0 + j + 8];
            float4 vA = h4[(size_t)sA * 8 + q];
            float4 vB = h4[(size_t)sB * 8 + q];
            acc_h8p(vA, vB, a);
        }
        if (j < dn) acc_h8(h4[(size_t)csr[s0 + j] * 8 + q], a);
#pragma unroll
        for (int off = 8; off < 64; off <<= 1) {
#pragma unroll
            for (int i = 0; i < 8; i++) a[i] += __shfl_xor(a[i], off, 64);
        }
        float di = dinv[node];
        if (eg == 0) {
            H8 u; u.f4 = h4[(size_t)node * 8 + q];
#pragma unroll
            for (int i = 0; i < 4; i++) {
                float2 fv = __half22float2(u.h2[i]);
                float r0 = di * (a[2 * i] + fv.x);
                float r1 = di * (a[2 * i + 1] + fv.y);
                half2v rp = {(_Float16)r0, (_Float16)r1};
                rowsp[grp][q * 4 + i] = rp;
            }
        }
        // wave-private LDS (compiler-ordered within the wave, no barrier)
        float acc = b1[lane];
#pragma unroll 8
        for (int k2 = 0; k2 < 32; k2++)
            acc = fdot2(rowsp[grp][k2], W1p[k2 * 64 + lane], acc);
        float h1v = fmaxf(acc, 0.0f);
        ((_Float16*)h1p[grp])[lane] = (_Float16)h1v;
        float p = 0.0f;
#pragma unroll 8
        for (int j2 = 0; j2 < 16; j2++) {
            int k2 = hf * 16 + j2;
            p = fdot2(h1p[grp][k2], W2p[k2 * 32 + f], p);
        }
        p += __shfl_xor(p, 32, 64);
        if (hf == 0) t2p[(size_t)node * 32 + f] = __float2half(di * p);
    }
}

// ---- fused: pull32(t2p16)+self -> h2=relu -> t3p16 = half(di*(h2@W3)) ----
// fdot2 matmul with W3 in LDS; rows stored as half2 (no bank conflicts).
__global__ __launch_bounds__(TPB) void k_pullfinmm32h(const int* __restrict__ row_start,
                                                      const int* __restrict__ deg,
                                                      const int* __restrict__ csr,
                                                      const float* __restrict__ dinv,
                                                      const __half* __restrict__ t2p,
                                                      const float* __restrict__ b2,
                                                      const float* __restrict__ W3,
                                                      __half* __restrict__ t3p, int N) {
    __shared__ half2v W3p[16 * 32];     // W3p[k2*32+f] = (W3[2k2][f], W3[2k2+1][f])
    __shared__ half2v rowsp[4][2][16];  // 32 halves per node slot
    int tid = threadIdx.x;
    for (int i = tid; i < 16 * 32; i += TPB) {
        int k2 = i >> 5, f = i & 31;
        half2v v = {(_Float16)W3[(2 * k2) * 32 + f], (_Float16)W3[(2 * k2 + 1) * 32 + f]};
        W3p[i] = v;
    }
    __syncthreads();
    int grp = tid >> 6, lane = tid & 63;
    int hw = lane >> 5, ll = lane & 31;
    int q = ll & 3, eg = ll >> 2;
    const float4* h4 = (const float4*)t2p;
    int n8 = (N + 7) >> 3;
    for (int blk = blockIdx.x; blk < n8; blk += gridDim.x) {
        int node = blk * 8 + grp * 2 + hw;
        if (node < N) {
            float di = dinv[node];
            int s0 = row_start[node], dn = deg[node];
            float a[8] = {0, 0, 0, 0, 0, 0, 0, 0};
            int j = eg;
            for (; j + 8 < dn; j += 16) {
                int sA = csr[s0 + j];
                int sB = csr[s0 + j + 8];
                float4 vA = h4[(size_t)sA * 4 + q];
                float4 vB = h4[(size_t)sB * 4 + q];
                acc_h8x2(vA, vB, a);
            }
            if (j < dn) acc_h8(h4[(size_t)csr[s0 + j] * 4 + q], a);
#pragma unroll
            for (int off = 4; off < 32; off <<= 1) {
#pragma unroll
                for (int i = 0; i < 8; i++) a[i] += __shfl_xor(a[i], off, 64);
            }
            if (eg == 0) {
                H8 u; u.f4 = h4[(size_t)node * 4 + q];
#pragma unroll
                for (int i = 0; i < 4; i++) {
                    float2 fv = __half22float2(u.h2[i]);
                    float r0 = fmaxf(di * (a[2 * i] + fv.x) + b2[q * 8 + 2 * i], 0.0f);
                    float r1 = fmaxf(di * (a[2 * i + 1] + fv.y) + b2[q * 8 + 2 * i + 1], 0.0f);
                    half2v rp = {(_Float16)r0, (_Float16)r1};
                    rowsp[grp][hw][q * 4 + i] = rp;
                }
            }
            float a2 = 0.0f;
#pragma unroll 8
            for (int k2 = 0; k2 < 16; k2++)
                a2 = fdot2(rowsp[grp][hw][k2], W3p[k2 * 32 + ll], a2);
            t3p[(size_t)node * 32 + ll] = __float2half(di * a2);
        }
    }
}

// ---- fused: pull32(t3p16)+self -> h3 = relu (fp32). 2 nodes/wave ----
__global__ __launch_bounds__(TPB) void k_pullfin3h(const int* __restrict__ row_start,
                                                   const int* __restrict__ deg,
                                                   const int* __restrict__ csr,
                                                   const float* __restrict__ dinv,
                                                   const __half* __restrict__ t3p,
                                                   const float* __restrict__ b3,
                                                   float* __restrict__ h3, int N) {
    int t = blockIdx.x * TPB + threadIdx.x;
    int node = t >> 5;
    int ll = t & 31;
    if (node >= N) return;
    int q = ll & 3, eg = ll >> 2;
    int s0 = row_start[node], dn = deg[node];
    const float4* h4 = (const float4*)t3p;
    float a[8] = {0, 0, 0, 0, 0, 0, 0, 0};
    int j = eg;
    for (; j + 8 < dn; j += 16) {
        int sA = csr[s0 + j];
        int sB = csr[s0 + j + 8];
        float4 vA = h4[(size_t)sA * 4 + q];
        float4 vB = h4[(size_t)sB * 4 + q];
        acc_h8x2(vA, vB, a);
    }
    if (j < dn) acc_h8(h4[(size_t)csr[s0 + j] * 4 + q], a);
#pragma unroll
    for (int off = 4; off < 32; off <<= 1) {
#pragma unroll
        for (int i = 0; i < 8; i++) a[i] += __shfl_xor(a[i], off, 64);
    }
    if (eg == 0) {
        float di = dinv[node];
        H8 u; u.f4 = h4[(size_t)node * 4 + q];
        float r[8];
#pragma unroll
        for (int i = 0; i < 4; i++) {
            float2 f = __half22float2(u.h2[i]);
            r[2 * i] = fmaxf(di * (a[2 * i] + f.x) + b3[q * 8 + 2 * i], 0.0f);
            r[2 * i + 1] = fmaxf(di * (a[2 * i + 1] + f.y) + b3[q * 8 + 2 * i + 1], 0.0f);
        }
        float4* o = (float4*)h3 + (size_t)node * 8 + q * 2;
        o[0] = make_float4(r[0], r[1], r[2], r[3]);
        o[1] = make_float4(r[4], r[5], r[6], r[7]);
    }
}

// ---------------- graph boundaries (batch_index is sorted) ----------------
__global__ __launch_bounds__(TPB) void k_gbound(const int* __restrict__ batch,
                                                int* __restrict__ start, int N, int G) {
    int g = blockIdx.x * TPB + threadIdx.x;
    if (g > G) return;
    int lo = 0, hi = N;
    while (lo < hi) {
        int mid = (lo + hi) >> 1;
        if (batch[mid] < g) lo = mid + 1;
        else hi = mid;
    }
    start[g] = lo;
}

// ---------------- pooling: one block per graph, no atomics ----------------
__global__ __launch_bounds__(TPB) void k_pool2(const float* __restrict__ h,
                                               const int* __restrict__ start,
                                               float* __restrict__ gmax,
                                               float* __restrict__ gsum, int G) {
    __shared__ float smax[8][32];
    __shared__ float ssum[8][32];
    int g = blockIdx.x;
    int s = start[g], e = start[g + 1];
    int tid = threadIdx.x;
    int nl = tid >> 5, f = tid & 31;
    float mx = 0.0f, sm = 0.0f;
    for (int n = s + nl; n < e; n += 8) {
        float v = h[(size_t)n * 32 + f];
        mx = fmaxf(mx, v);
        sm += v;
    }
    smax[nl][f] = mx;
    ssum[nl][f] = sm;
    __syncthreads();
    if (nl == 0) {
#pragma unroll
        for (int k = 1; k < 8; k++) {
            mx = fmaxf(mx, smax[k][f]);
            sm += ssum[k][f];
        }
        gmax[g * 32 + f] = mx;
        gsum[g * 32 + f] = sm;
    }
}

// ---------------- head ----------------
__global__ __launch_bounds__(TPB) void k_out(const float* __restrict__ gmax,
                                             const float* __restrict__ gsum,
                                             const int* __restrict__ start,
                                             const float* __restrict__ Wout,
                                             const float* __restrict__ bout,
                                             float* __restrict__ out, int G) {
    int t = blockIdx.x * TPB + threadIdx.x;
    if (t >= G * 10) return;
    int g = t / 10, j = t % 10;
    float c = (float)(start[g + 1] - start[g]);
    float inv = 1.0f / fmaxf(c, 1.0f);
    float a = bout[j];
#pragma unroll
    for (int k = 0; k < 32; k++) a += gmax[g * 32 + k] * Wout[k * 10 + j];
#pragma unroll
    for (int k = 0; k < 32; k++) a += (gsum[g * 32 + k] * inv) * Wout[(32 + k) * 10 + j];
    out[t] = a;
}

static inline int cdiv(long long a, int b) { return (int)((a + b - 1) / b); }

extern "C" void kernel_launch(void* const* d_in, const int* in_sizes, int n_in,
                              void* d_out, int out_size, void* d_ws, size_t ws_size,
                              hipStream_t stream) {
    const float* x    = (const float*)d_in[0];
    const int*   ei   = (const int*)d_in[1];
    const int*   bidx = (const int*)d_in[2];
    const float* W0 = (const float*)d_in[3];
    const float* b0 = (const float*)d_in[4];
    const float* W1 = (const float*)d_in[5];
    const float* b1 = (const float*)d_in[6];
    const float* W2 = (const float*)d_in[7];
    const float* b2 = (const float*)d_in[8];
    const float* W3 = (const float*)d_in[9];
    const float* b3 = (const float*)d_in[10];
    const float* Wout = (const float*)d_in[11];
    const float* bout = (const float*)d_in[12];
    float* out = (float*)d_out;

    const int N = in_sizes[0] / 8;
    const int E = in_sizes[1] / 2;
    const int G = out_size / 10;
    const int* src = ei;
    const int* dst = ei + E;

    int shift = 10;
    while (((N + (1 << shift) - 1) >> shift) > 256) shift++;
    const int nbuck = (N + (1 << shift) - 1) >> shift;

    // ---- workspace layout (16B-aligned chunks) ----
    char* w = (char*)d_ws;
    int*   deg_i     = (int*)w;    w += (size_t)N * 4;
    int*   row_start = (int*)w;    w += (size_t)N * 4;
    float* dinv      = (float*)w;  w += (size_t)N * 4;
    float* gmax      = (float*)w;  w += (size_t)G * 32 * 4;
    float* gsum      = (float*)w;  w += (size_t)G * 32 * 4;
    int*   gstart    = (int*)w;    w += (size_t)(G + 4) * 4;
    int*   bhist     = (int*)w;    w += 256 * 4;
    int*   bstart    = (int*)w;    w += 260 * 4;
    int*   csr       = (int*)w;    w += (size_t)E * 4;
    float* bufA      = (float*)w;  w += (size_t)N * 64 * 4;
    float* bufB      = (float*)w;  w += (size_t)N * 64 * 4;
    // transient aliases (stream-ordered lifetimes):
    unsigned* staging = (unsigned*)bufA;   // E recs; dead after k_scatter2
    int*      gcursor = (int*)bufB;        // nbuck; dead after k_part
    __half* xp16  = (__half*)bufB;         // N*8 h; written after k_part; dead after l0fused
    __half* h0p16 = (__half*)bufA;         // N*64 h; dead after k_pullmmf
    __half* t2p16 = (__half*)bufB;         // N*32 h; dead after k_pullfinmm32h
    __half* t3p16 = (__half*)bufA;         // N*32 h; dead after k_pullfin3h
    float*  h3    = (float*)bufB;          // N*32 f

    // ---- CSR build ----
    hipMemsetAsync(bhist, 0, 256 * 4, stream);
    k_bhist<<<256, TPB, 0, stream>>>(dst, bhist, E, shift);
    k_bscan<<<1, 256, 0, stream>>>(bhist, bstart, gcursor, nbuck);
    k_part<<<NB_PART, TPB, 0, stream>>>(src, dst, gcursor, staging, E, shift);
    k_deg_scan<<<nbuck, TPB, 0, stream>>>(staging, bstart, deg_i, dinv, row_start, N, shift);
    k_scatter2<<<nbuck, TPB, 0, stream>>>(staging, row_start, csr, N, E, shift);
    k_gbound<<<cdiv(G + 1, TPB), TPB, 0, stream>>>(bidx, gstart, N, G);

    // ---- layer 0 (fp16 gathers, fp32 math) ----
    k_xp16<<<cdiv((long long)N * 8, TPB), TPB, 0, stream>>>(x, dinv, xp16, N);
    k_l0fused<<<cdiv(N, 16), TPB, 0, stream>>>(row_start, deg_i, csr, dinv, xp16, W0, b0,
                                               h0p16, N);

    // ---- layers 1+2a fused: pull64 + W1 + relu + W2 + scale -> t2p16 ----
    k_pullmmf<<<NB_LOOP, TPB, 0, stream>>>(row_start, deg_i, csr, dinv, h0p16, W1, b1, W2,
                                           t2p16, N);

    // ---- layer 2b+3a: fused pull32 + fin + W3 + scale -> t3p16 ----
    k_pullfinmm32h<<<NB_LOOP, TPB, 0, stream>>>(row_start, deg_i, csr, dinv, t2p16, b2,
                                                W3, t3p16, N);

    // ---- layer 3b: fused pull32 + finalize -> h3 (flat grid) ----
    k_pullfin3h<<<cdiv(N, 8), TPB, 0, stream>>>(row_start, deg_i, csr, dinv, t3p16, b3, h3, N);

    // ---- pooling + head ----
    k_pool2<<<G, TPB, 0, stream>>>(h3, gstart, gmax, gsum, G);
    k_out<<<cdiv((long long)G * 10, TPB), TPB, 0, stream>>>(gmax, gsum, gstart, Wout, bout,
                                                            out, G);
}